// Round 16
// baseline (247.542 us; speedup 1.0000x reference)
//
#include <hip/hip_runtime.h>

#define NN 8
#define HH 512
#define WW 512
#define CC 3
#define KK 5
#define PADP 2
#define WROWF (WW * CC)          // 1536 floats per image row
#define NBLOCKS 4096             // n(8) x hg(64) x wseg(8); block walks 4 row-pairs down

typedef float f4a __attribute__((ext_vector_type(4), aligned(4)));

struct Row { f4a L0, L1, L2, L3; };   // 15-float window f0..f14 (L3 overlaps at f11)

__device__ __forceinline__ void load_row(const float* rb, Row& r) {
    r.L0 = *(const f4a*)(rb);
    r.L1 = *(const f4a*)(rb + 4);
    r.L2 = *(const f4a*)(rb + 8);
    r.L3 = *(const f4a*)(rb + 11);
}

__device__ __forceinline__ void fma_row(const Row& r, const float* wp,
                                        float& a0, float& a1, float& a2) {
    const float w0 = wp[0], w1 = wp[1], w2 = wp[2], w3 = wp[3], w4 = wp[4];
    a0 = fmaf(r.L0[0], w0, a0); a1 = fmaf(r.L0[1], w0, a1); a2 = fmaf(r.L0[2], w0, a2);
    a0 = fmaf(r.L0[3], w1, a0); a1 = fmaf(r.L1[0], w1, a1); a2 = fmaf(r.L1[1], w1, a2);
    a0 = fmaf(r.L1[2], w2, a0); a1 = fmaf(r.L1[3], w2, a1); a2 = fmaf(r.L2[0], w2, a2);
    a0 = fmaf(r.L2[1], w3, a0); a1 = fmaf(r.L2[2], w3, a1); a2 = fmaf(r.L2[3], w3, a2);
    a0 = fmaf(r.L3[1], w4, a0); a1 = fmaf(r.L3[2], w4, a1); a2 = fmaf(r.L3[3], w4, a2);
}

#define GLDS16(gp, lp) __builtin_amdgcn_global_load_lds( \
    (const __attribute__((address_space(1))) void*)(gp), \
    (__attribute__((address_space(3))) void*)(lp), 16, 0, 0)
#define GLDS4(gp, lp) __builtin_amdgcn_global_load_lds( \
    (const __attribute__((address_space(1))) void*)(gp), \
    (__attribute__((address_space(3))) void*)(lp), 4, 0, 0)

// stage weights for rows 2*hp (bufA) and 2*hp+1 (bufB): exactly 14 VMEM ops
#define STAGE2(hp) do {                                                  \
    const long _p = (long)(nHH + ((hp) << 1)) * WW + w0;                 \
    const char* _s0 = (const char*)(wt + _p * (KK * KK));                \
    const char* _s1 = (const char*)(wt + (_p + WW) * (KK * KK));         \
    _Pragma("unroll")                                                    \
    for (int _it = 0; _it < 6; ++_it)                                    \
        GLDS16(_s0 + _it * 1024 + lane * 16, bufA + _it * 256);          \
    GLDS4(_s0 + 6144 + lane * 4, bufA + 1536);                           \
    _Pragma("unroll")                                                    \
    for (int _it = 0; _it < 6; ++_it)                                    \
        GLDS16(_s1 + _it * 1024 + lane * 16, bufB + _it * 256);          \
    GLDS4(_s1 + 6144 + lane * 4, bufB + 1536);                           \
} while (0)

#define WAITV0() do {                                                    \
    asm volatile("s_waitcnt vmcnt(0)" ::: "memory");                     \
    __builtin_amdgcn_sched_barrier(0);                                   \
} while (0)

#define LGKM0() do {                                                     \
    asm volatile("s_waitcnt lgkmcnt(0)" ::: "memory");                   \
    __builtin_amdgcn_sched_barrier(0);                                   \
} while (0)

// load one input row (clamped row index) into a Row register set
#define LOADR(Rv, ridx) do {                                             \
    int _r = (ridx);                                                     \
    _r = _r < 0 ? 0 : (_r > HH - 1 ? HH - 1 : _r);                       \
    load_row(inb + (long)_r * WROWF + colb, Rv);                         \
} while (0)

// fast dual-row compute (rows 2hp, 2hp+1) + 2-lane border fixup + stores
#define FASTC(Ra, Rb, Rc, Rd, Re, Rf, hp) do {                           \
    const float* wp0 = &bufA[lane * (KK * KK)];                          \
    const float* wp1 = &bufB[lane * (KK * KK)];                          \
    float a0 = 0.f, a1 = 0.f, a2 = 0.f;                                  \
    float d0 = 0.f, d1 = 0.f, d2 = 0.f;                                  \
    fma_row(Ra, wp0 + 0,  a0, a1, a2);                                   \
    fma_row(Rb, wp0 + 5,  a0, a1, a2);                                   \
    fma_row(Rb, wp1 + 0,  d0, d1, d2);                                   \
    fma_row(Rc, wp0 + 10, a0, a1, a2);                                   \
    fma_row(Rc, wp1 + 5,  d0, d1, d2);                                   \
    fma_row(Rd, wp0 + 15, a0, a1, a2);                                   \
    fma_row(Rd, wp1 + 10, d0, d1, d2);                                   \
    fma_row(Re, wp0 + 20, a0, a1, a2);                                   \
    fma_row(Re, wp1 + 15, d0, d1, d2);                                   \
    fma_row(Rf, wp1 + 20, d0, d1, d2);                                   \
    const int _w = w0 + lane;                                            \
    if (_w < PADP || _w >= WW - PADP) {   /* exec-masked: wseg 0/7 only */ \
        const int _h0 = (hp) << 1;                                       \
        a0 = 0.f; a1 = 0.f; a2 = 0.f; d0 = 0.f; d1 = 0.f; d2 = 0.f;      \
        _Pragma("unroll")                                                \
        for (int dh = 0; dh < KK; ++dh) {                                \
            _Pragma("unroll")                                            \
            for (int dw = 0; dw < KK; ++dw) {                            \
                const int iw = _w + dw - PADP;                           \
                const bool ok = ((unsigned)iw < (unsigned)WW);           \
                const float* pa = inb + ((long)(_h0 + dh - PADP) * WW + iw) * CC; \
                const float* pd = pa + WROWF;                            \
                float va0 = ok ? pa[0] : 0.f, va1 = ok ? pa[1] : 0.f, va2 = ok ? pa[2] : 0.f; \
                float vd0 = ok ? pd[0] : 0.f, vd1 = ok ? pd[1] : 0.f, vd2 = ok ? pd[2] : 0.f; \
                const float wa = wp0[dh * KK + dw];                      \
                const float wd = wp1[dh * KK + dw];                      \
                a0 = fmaf(va0, wa, a0); a1 = fmaf(va1, wa, a1); a2 = fmaf(va2, wa, a2); \
                d0 = fmaf(vd0, wd, d0); d1 = fmaf(vd1, wd, d1); d2 = fmaf(vd2, wd, d2); \
            }                                                            \
        }                                                                \
    }                                                                    \
    float* _o0 = out + ((long)(nHH + ((hp) << 1)) * WW + _w) * CC;       \
    _o0[0] = a0; _o0[1] = a1; _o0[2] = a2;                               \
    float* _o1 = _o0 + WROWF * 1;                                        \
    _o1[0] = d0; _o1[1] = d1; _o1[2] = d2;                               \
} while (0)

// border-row step (hp = 0 or 255): fully predicated scalar, weights from LDS
#define SCALAR2(hp) do {                                                 \
    const float* _wpA = &bufA[lane * (KK * KK)];                         \
    const float* _wpB = &bufB[lane * (KK * KK)];                         \
    const int _w = w0 + lane;                                            \
    _Pragma("unroll")                                                    \
    for (int px = 0; px < 2; ++px) {                                     \
        const int hh = (((hp) << 1)) + px;                               \
        const float* wp = px ? _wpB : _wpA;                              \
        float a0 = 0.f, a1 = 0.f, a2 = 0.f;                              \
        _Pragma("unroll")                                                \
        for (int dh = 0; dh < KK; ++dh) {                                \
            const int ih = hh + dh - PADP;                               \
            const bool rok = ((unsigned)ih < (unsigned)HH);              \
            _Pragma("unroll")                                            \
            for (int dw = 0; dw < KK; ++dw) {                            \
                const int iw = _w + dw - PADP;                           \
                const bool ok = rok && ((unsigned)iw < (unsigned)WW);    \
                const float* p = inb + ((long)(ih * WW + iw)) * CC;      \
                float v0 = ok ? p[0] : 0.f;                              \
                float v1 = ok ? p[1] : 0.f;                              \
                float v2 = ok ? p[2] : 0.f;                              \
                const float wv = wp[dh * KK + dw];                       \
                a0 = fmaf(v0, wv, a0);                                   \
                a1 = fmaf(v1, wv, a1);                                   \
                a2 = fmaf(v2, wv, a2);                                   \
            }                                                            \
        }                                                                \
        float* _o = out + ((long)(nHH + hh) * WW + _w) * CC;             \
        _o[0] = a0; _o[1] = a1; _o[2] = a2;                              \
    }                                                                    \
} while (0)

// one pipeline step s: drain, compute row-pair hp, roll 2 input rows, stage next
#define STEP(s, Ra, Rb, Rc, Rd, Re, Rf, FAST) do {                       \
    const int _hp = (hg << 2) + (s);                                     \
    WAITV0();                                                            \
    if (FAST) { FASTC(Ra, Rb, Rc, Rd, Re, Rf, _hp); }                    \
    else      { SCALAR2(_hp); }                                          \
    if ((s) < 3) {                                                       \
        LOADR(Ra, (hg << 3) + 2 * (s) + 4);                              \
        LOADR(Rb, (hg << 3) + 2 * (s) + 5);                              \
        LGKM0();                                                         \
        STAGE2(_hp + 1);                                                 \
    }                                                                    \
} while (0)

__global__ __launch_bounds__(64, 3) void conv_local_kernel(
    const float* __restrict__ in,   // (N,H,W,C)
    const float* __restrict__ wt,   // (N,H,W,25)
    float* __restrict__ out)        // (N,H,W,C)
{
    __shared__ float bufA[64 * KK * KK];   // 6.4 KB: even-row weights
    __shared__ float bufB[64 * KK * KK];   // 6.4 KB: odd-row weights -> 12 blocks/CU

    const int lane = threadIdx.x;
    // bijective XCD swizzle: 4096 = 8 x 512; XCD k works image k; wseg fastest
    // so consecutive blocks on an XCD share input rows in L2.
    const int b    = ((blockIdx.x & 7) << 9) | (blockIdx.x >> 3);
    const int n    = b >> 9;
    const int rem  = b & 511;
    const int hg   = rem >> 3;          // 0..63: rows 8*hg .. 8*hg+7
    const int wseg = rem & 7;
    const int w0   = wseg << 6;
    const int nHH  = n * HH;

    const float* inb = in + (size_t)n * (HH * WW * CC);

    // clamped column base (lanes at image edge fixed up in FASTC)
    int colc = w0 + lane - PADP;
    colc = colc < 0 ? 0 : (colc > WW - 5 ? WW - 5 : colc);
    const int colb = colc * CC;

    // prologue: step-0 weights + 6-row input window in flight together
    STAGE2(hg << 2);
    Row R0, R1, R2, R3, R4, R5;
    {
        const int B = hg << 3;
        LOADR(R0, B - 2);
        LOADR(R1, B - 1);
        LOADR(R2, B + 0);
        LOADR(R3, B + 1);
        LOADR(R4, B + 2);
        LOADR(R5, B + 3);
    }

    // 4 steps, register window rolls by 2 rows each step
    STEP(0, R0, R1, R2, R3, R4, R5, (hg != 0));
    STEP(1, R2, R3, R4, R5, R0, R1, true);
    STEP(2, R4, R5, R0, R1, R2, R3, true);
    STEP(3, R0, R1, R2, R3, R4, R5, (hg != 63));
}

extern "C" void kernel_launch(void* const* d_in, const int* in_sizes, int n_in,
                              void* d_out, int out_size, void* d_ws, size_t ws_size,
                              hipStream_t stream) {
    const float* in = (const float*)d_in[0];   // (8,512,512,3) f32
    const float* wt = (const float*)d_in[1];   // (8,512,512,25) f32
    float* out = (float*)d_out;                // (8,512,512,3) f32

    conv_local_kernel<<<NBLOCKS, 64, 0, stream>>>(in, wt, out);
}

// Round 17
// 56.249 us; speedup vs baseline: 4.4008x; 4.4008x over previous
//
#include <hip/hip_runtime.h>

#define NN 8
#define HH 512
#define WW 512
#define CC 3
#define KK 5
#define PADP 2
#define WROWF (WW * CC)          // 1536 floats per image row
#define NBLOCKS 4096             // (n, h-pair, half-row walk): 8 * 256 * 2

typedef float f4a __attribute__((ext_vector_type(4), aligned(4)));

struct Row { f4a L0, L1, L2, L3; };   // 15-float window f0..f14 (L3 overlaps at f11)

__device__ __forceinline__ void load_row(const float* rb, Row& r) {
    r.L0 = *(const f4a*)(rb);
    r.L1 = *(const f4a*)(rb + 4);
    r.L2 = *(const f4a*)(rb + 8);
    r.L3 = *(const f4a*)(rb + 11);
}

__device__ __forceinline__ void fma_row(const Row& r, const float* wp,
                                        float& a0, float& a1, float& a2) {
    const float w0 = wp[0], w1 = wp[1], w2 = wp[2], w3 = wp[3], w4 = wp[4];
    a0 = fmaf(r.L0[0], w0, a0); a1 = fmaf(r.L0[1], w0, a1); a2 = fmaf(r.L0[2], w0, a2);
    a0 = fmaf(r.L0[3], w1, a0); a1 = fmaf(r.L1[0], w1, a1); a2 = fmaf(r.L1[1], w1, a2);
    a0 = fmaf(r.L1[2], w2, a0); a1 = fmaf(r.L1[3], w2, a1); a2 = fmaf(r.L2[0], w2, a2);
    a0 = fmaf(r.L2[1], w3, a0); a1 = fmaf(r.L2[2], w3, a1); a2 = fmaf(r.L2[3], w3, a2);
    a0 = fmaf(r.L3[1], w4, a0); a1 = fmaf(r.L3[2], w4, a1); a2 = fmaf(r.L3[3], w4, a2);
}

#define GLDS16(gp, lp) __builtin_amdgcn_global_load_lds( \
    (const __attribute__((address_space(1))) void*)(gp), \
    (__attribute__((address_space(3))) void*)(lp), 16, 0, 0)
#define GLDS4(gp, lp) __builtin_amdgcn_global_load_lds( \
    (const __attribute__((address_space(1))) void*)(gp), \
    (__attribute__((address_space(3))) void*)(lp), 4, 0, 0)

__global__ __launch_bounds__(64, 4) void conv_local_kernel(
    const float* __restrict__ in,   // (N,H,W,C)
    const float* __restrict__ wt,   // (N,H,W,25)
    float* __restrict__ out)        // (N,H,W,C)
{
    __shared__ float wldsA[64 * KK * KK];   // 6.4 KB: row h0 weights
    __shared__ float wldsB[64 * KK * KK];   // 6.4 KB: row h0+1 weights

    const int lane = threadIdx.x;
    // bijective XCD swizzle: 4096 = 8 x 512; XCD k streams image k only
    const int b    = ((blockIdx.x & 7) << 9) | (blockIdx.x >> 3);
    const int n    = b >> 9;
    const int rem  = b & 511;
    const int hp   = rem >> 1;         // 0..255
    const int half = rem & 1;          // walks wseg half*4 .. half*4+3
    const int h0   = hp << 1;          // 0..510 (rows h0, h0+1)
    const int nHH  = n * HH;

    const float* inb  = in + (size_t)n * (HH * WW * CC);
    const bool  rowok = (hp >= 1) && (hp <= 254);   // h0-2 >= 0 && h0+4 <= 511

#pragma unroll 1
    for (int j = 0; j < 4; ++j) {
        const int  w0 = (((half << 2) | j)) << 6;   // contiguous weight walk
        const long p0 = (long)(nHH + h0) * WW + w0;
        const long p1 = p0 + WW;

        // previous step's ds_reads are complete (results consumed); belt-and-braces:
        asm volatile("s_waitcnt lgkmcnt(0)" ::: "memory");

        // ---- stage both rows' weights: 14 async GLDS ops, two contiguous streams ----
        {
            const char* s0 = (const char*)(wt + p0 * (KK * KK));
            const char* s1 = (const char*)(wt + p1 * (KK * KK));
#pragma unroll
            for (int it = 0; it < 6; ++it)
                GLDS16(s0 + it * 1024 + lane * 16, wldsA + it * 256);
            GLDS4(s0 + 6144 + lane * 4, wldsA + 1536);
#pragma unroll
            for (int it = 0; it < 6; ++it)
                GLDS16(s1 + it * 1024 + lane * 16, wldsB + it * 256);
            GLDS4(s1 + 6144 + lane * 4, wldsB + 1536);
        }

        const float* wp0 = &wldsA[lane * (KK * KK)];
        const float* wp1 = &wldsB[lane * (KK * KK)];
        const bool fast = rowok && (w0 != 0) && (w0 != WW - 64);

        if (fast) {
            // 6 input rows h0-2 .. h0+3 upfront (L2-hot; latency hides under wt drain)
            const float* rb = inb + ((long)(h0 - PADP) * WW + (w0 + lane - PADP)) * CC;
            Row R0, R1, R2, R3, R4, R5;
            load_row(rb + 0 * WROWF, R0);
            load_row(rb + 1 * WROWF, R1);
            load_row(rb + 2 * WROWF, R2);
            load_row(rb + 3 * WROWF, R3);
            load_row(rb + 4 * WROWF, R4);
            load_row(rb + 5 * WROWF, R5);
            asm volatile("s_waitcnt vmcnt(0)" ::: "memory");
            __builtin_amdgcn_sched_barrier(0);

            float a0 = 0.f, a1 = 0.f, a2 = 0.f;   // px (h0,   w)
            float c0 = 0.f, c1 = 0.f, c2 = 0.f;   // px (h0+1, w)
            fma_row(R0, wp0 + 0,  a0, a1, a2);
            fma_row(R1, wp0 + 5,  a0, a1, a2);
            fma_row(R1, wp1 + 0,  c0, c1, c2);
            fma_row(R2, wp0 + 10, a0, a1, a2);
            fma_row(R2, wp1 + 5,  c0, c1, c2);
            fma_row(R3, wp0 + 15, a0, a1, a2);
            fma_row(R3, wp1 + 10, c0, c1, c2);
            fma_row(R4, wp0 + 20, a0, a1, a2);
            fma_row(R4, wp1 + 15, c0, c1, c2);
            fma_row(R5, wp1 + 20, c0, c1, c2);

            float* o0 = out + (p0 + lane) * CC;
            o0[0] = a0; o0[1] = a1; o0[2] = a2;
            float* o1 = out + (p1 + lane) * CC;
            o1[0] = c0; o1[1] = c1; o1[2] = c2;
        } else {
            asm volatile("s_waitcnt vmcnt(0)" ::: "memory");
            __builtin_amdgcn_sched_barrier(0);
            // border step: predicated scalar path (R1-proven), weights from LDS
#pragma unroll
            for (int px = 0; px < 2; ++px) {
                const int hh = h0 + px;
                const int w  = w0 + lane;
                const float* wp = px ? wp1 : wp0;
                float a0 = 0.f, a1 = 0.f, a2 = 0.f;
#pragma unroll
                for (int dh = 0; dh < KK; ++dh) {
                    const int ih = hh + dh - PADP;
                    const bool rok = ((unsigned)ih < (unsigned)HH);
#pragma unroll
                    for (int dw = 0; dw < KK; ++dw) {
                        const int iw = w + dw - PADP;
                        const bool ok = rok && ((unsigned)iw < (unsigned)WW);
                        const float* p = inb + ((long)(ih * WW + iw)) * CC;
                        float v0 = ok ? p[0] : 0.f;
                        float v1 = ok ? p[1] : 0.f;
                        float v2 = ok ? p[2] : 0.f;
                        const float wv = wp[dh * KK + dw];
                        a0 = fmaf(v0, wv, a0);
                        a1 = fmaf(v1, wv, a1);
                        a2 = fmaf(v2, wv, a2);
                    }
                }
                float* o = out + ((long)(nHH + hh) * WW + w) * CC;
                o[0] = a0; o[1] = a1; o[2] = a2;
            }
        }
    }
}

extern "C" void kernel_launch(void* const* d_in, const int* in_sizes, int n_in,
                              void* d_out, int out_size, void* d_ws, size_t ws_size,
                              hipStream_t stream) {
    const float* in = (const float*)d_in[0];   // (8,512,512,3) f32
    const float* wt = (const float*)d_in[1];   // (8,512,512,25) f32
    float* out = (float*)d_out;                // (8,512,512,3) f32

    conv_local_kernel<<<NBLOCKS, 64, 0, stream>>>(in, wt, out);
}